// Round 1
// baseline (24729.610 us; speedup 1.0000x reference)
//
#include <hip/hip_runtime.h>
#include <hip/hip_bf16.h>

#define TSTEPS 256
#define BATCH  64
#define NTOK   256
#define NINP   64
#define NHID   4096
#define NGATE  (4 * NHID)        // 16384
#define KDIM   (NINP + NHID)     // 4160
#define KHALF  (KDIM / 2)        // 2080

typedef __bf16 bf16x8 __attribute__((ext_vector_type(8)));
typedef float  f32x4  __attribute__((ext_vector_type(4)));

__device__ __forceinline__ unsigned short f2b(float v) {
    __hip_bfloat16 h = __float2bfloat16(v);
    return *reinterpret_cast<unsigned short*>(&h);
}
__device__ __forceinline__ float sigf(float x) { return 1.f / (1.f + expf(-x)); }

// ---- pack [w_ih | w_hh] -> bf16 W[NGATE][KDIM], bias = b_ih + b_hh ----
__global__ void k_convert(const float* __restrict__ w_ih, const float* __restrict__ w_hh,
                          const float* __restrict__ b_ih, const float* __restrict__ b_hh,
                          unsigned short* __restrict__ W, float* __restrict__ bias) {
    int g = blockIdx.x;                       // 0..NGATE-1
    const float* sih = w_ih + (long)g * NINP;
    const float* shh = w_hh + (long)g * NHID;
    unsigned short* dst = W + (long)g * KDIM;
    for (int k = threadIdx.x; k < KDIM; k += 256) {
        float v = (k < NINP) ? sih[k] : shh[k - NINP];
        dst[k] = f2b(v);
    }
    if (threadIdx.x == 0) bias[g] = b_ih[g] + b_hh[g];
}

// ---- init A0 = [emb(tokens[0]) | 0] bf16, c = 0 ----
__global__ void k_init(const int* __restrict__ tokens, const float* __restrict__ emb,
                       unsigned short* __restrict__ A0, float* __restrict__ c) {
    int idx = blockIdx.x * 256 + threadIdx.x;
    if (idx < BATCH * KDIM) {
        int b = idx / KDIM, k = idx - b * KDIM;
        float v = 0.f;
        if (k < NINP) v = emb[tokens[b] * NINP + k];
        A0[idx] = f2b(v);
    }
    if (idx < BATCH * NHID) c[idx] = 0.f;
}

// ---- one LSTM step ----
// grid: 256 blocks (16 hidden cols each), 512 threads (8 waves = 4 gate types x 2 K halves)
__global__ __launch_bounds__(512)
void k_step(int t, const unsigned short* __restrict__ W, const float* __restrict__ bias,
            const unsigned short* __restrict__ Acur, unsigned short* __restrict__ Anext,
            float* __restrict__ cbuf, float* __restrict__ out,
            const int* __restrict__ tokens, const int* __restrict__ seq_len,
            const float* __restrict__ emb) {
    const int tid   = threadIdx.x;
    const int wave  = tid >> 6;           // 0..7
    const int lane  = tid & 63;
    const int gtype = wave & 3;           // i,f,g,o
    const int khalf = wave >> 2;          // 0/1
    const int j0    = blockIdx.x * 16;
    const int gbase = gtype * NHID + j0;

    const int n  = lane & 15;             // N col within tile / A row selector
    const int kq = (lane >> 4) * 8;       // k sub-offset within 32

    const unsigned short* wptr = W    + (gbase + n) * KDIM + khalf * KHALF + kq;
    const unsigned short* aptr = Acur + n * KDIM            + khalf * KHALF + kq;

    f32x4 acc0 = {0.f, 0.f, 0.f, 0.f};
    f32x4 acc1 = {0.f, 0.f, 0.f, 0.f};
    f32x4 acc2 = {0.f, 0.f, 0.f, 0.f};
    f32x4 acc3 = {0.f, 0.f, 0.f, 0.f};

    for (int k = 0; k < KHALF; k += 32) {
        bf16x8 bf = *reinterpret_cast<const bf16x8*>(wptr + k);
        bf16x8 a0 = *reinterpret_cast<const bf16x8*>(aptr + k);
        bf16x8 a1 = *reinterpret_cast<const bf16x8*>(aptr + 16 * KDIM + k);
        bf16x8 a2 = *reinterpret_cast<const bf16x8*>(aptr + 32 * KDIM + k);
        bf16x8 a3 = *reinterpret_cast<const bf16x8*>(aptr + 48 * KDIM + k);
        acc0 = __builtin_amdgcn_mfma_f32_16x16x32_bf16(a0, bf, acc0, 0, 0, 0);
        acc1 = __builtin_amdgcn_mfma_f32_16x16x32_bf16(a1, bf, acc1, 0, 0, 0);
        acc2 = __builtin_amdgcn_mfma_f32_16x16x32_bf16(a2, bf, acc2, 0, 0, 0);
        acc3 = __builtin_amdgcn_mfma_f32_16x16x32_bf16(a3, bf, acc3, 0, 0, 0);
    }

    // bias only once (khalf 0)
    float bv = (khalf == 0) ? bias[gbase + n] : 0.f;

    // LDS exchange: gbuf[wave][batch 64][16 cols], stride 17 to break bank conflicts
    __shared__ float gbuf[8][BATCH][17];
    const int q = lane >> 4;
    {
        f32x4 av[4] = {acc0, acc1, acc2, acc3};
        #pragma unroll
        for (int mt = 0; mt < 4; ++mt)
            #pragma unroll
            for (int r = 0; r < 4; ++r)
                gbuf[wave][mt * 16 + q * 4 + r][n] = av[mt][r] + bv;
    }
    __syncthreads();

    // cell update: wave handles 2 cols, lane = batch
    {
        const int b  = lane;
        const int sl = seq_len[b];
        const bool valid = (t < sl) || (t == 0);
        #pragma unroll
        for (int jj = 0; jj < 2; ++jj) {
            int jl = wave * 2 + jj;       // 0..15
            float ig = gbuf[0][b][jl] + gbuf[4][b][jl];
            float fg = gbuf[1][b][jl] + gbuf[5][b][jl];
            float gg = gbuf[2][b][jl] + gbuf[6][b][jl];
            float og = gbuf[3][b][jl] + gbuf[7][b][jl];
            int j = j0 + jl;
            int cidx = b * NHID + j;
            float cold = cbuf[cidx];
            float cn = sigf(fg) * cold + sigf(ig) * tanhf(gg);
            float hn = sigf(og) * tanhf(cn);
            cbuf[cidx] = cn;
            if (valid) out[cidx] = cn;
            Anext[b * KDIM + NINP + j] = f2b(hn);
        }
    }

    // block 0 writes next step's embedding rows into Anext
    if (blockIdx.x == 0 && (t + 1) < TSTEPS) {
        for (int i = tid; i < BATCH * NINP; i += 512) {
            int b = i >> 6, k = i & 63;
            int tok = tokens[(t + 1) * BATCH + b];
            Anext[b * KDIM + k] = f2b(emb[tok * NINP + k]);
        }
    }
}

extern "C" void kernel_launch(void* const* d_in, const int* in_sizes, int n_in,
                              void* d_out, int out_size, void* d_ws, size_t ws_size,
                              hipStream_t stream) {
    const int*   tokens  = (const int*)d_in[0];
    const int*   seq_len = (const int*)d_in[1];
    const float* emb     = (const float*)d_in[2];
    const float* w_ih    = (const float*)d_in[3];
    const float* w_hh    = (const float*)d_in[4];
    const float* b_ih    = (const float*)d_in[5];
    const float* b_hh    = (const float*)d_in[6];
    float* out = (float*)d_out;

    char* ws = (char*)d_ws;
    const size_t W_BYTES    = (size_t)NGATE * KDIM * 2;   // 136,314,880
    const size_t BIAS_BYTES = (size_t)NGATE * 4;          // 65,536
    const size_t C_BYTES    = (size_t)BATCH * NHID * 4;   // 1,048,576
    const size_t A_BYTES    = (size_t)BATCH * KDIM * 2;   // 532,480

    unsigned short* W    = (unsigned short*)ws;
    float*          bias = (float*)(ws + W_BYTES);
    float*          cbuf = (float*)(ws + W_BYTES + BIAS_BYTES);
    unsigned short* A0   = (unsigned short*)(ws + W_BYTES + BIAS_BYTES + C_BYTES);
    unsigned short* A1   = (unsigned short*)(ws + W_BYTES + BIAS_BYTES + C_BYTES + A_BYTES);

    k_convert<<<NGATE, 256, 0, stream>>>(w_ih, w_hh, b_ih, b_hh, W, bias);

    int init_elems = BATCH * KDIM;  // covers c too (BATCH*NHID < BATCH*KDIM)
    k_init<<<(init_elems + 255) / 256, 256, 0, stream>>>(tokens, emb, A0, cbuf);

    for (int t = 0; t < TSTEPS; ++t) {
        unsigned short* Ac = (t & 1) ? A1 : A0;
        unsigned short* An = (t & 1) ? A0 : A1;
        k_step<<<256, 512, 0, stream>>>(t, W, bias, Ac, An, cbuf, out,
                                        tokens, seq_len, emb);
    }
}

// Round 2
// 17227.513 us; speedup vs baseline: 1.4355x; 1.4355x over previous
//
#include <hip/hip_runtime.h>
#include <hip/hip_bf16.h>

#define TSTEPS 256
#define BATCH  64
#define NINP   64
#define NHID   4096
#define NGATE  (4 * NHID)        // 16384
#define KDIM   (NINP + NHID)     // 4160
#define NCHUNK (KDIM / 32)       // 130 chunks of 32 k-values
#define NGRP   (NGATE / 16)      // 1024 groups of 16 gate rows

typedef __bf16 bf16x8 __attribute__((ext_vector_type(8)));
typedef float  f32x4  __attribute__((ext_vector_type(4)));
typedef unsigned short ushort_t;

__device__ __forceinline__ ushort_t f2b(float v) {
    __hip_bfloat16 h = __float2bfloat16(v);
    return *reinterpret_cast<ushort_t*>(&h);
}
__device__ __forceinline__ float sigf(float x) { return 1.f / (1.f + expf(-x)); }

// Fragment-linear layout:
//   W'[grp][chunk][lane][8]  : lane = q*16 + n holds row (grp*16+n), k = chunk*32 + q*8 .. +8
//   A'[rt ][chunk][lane][8]  : lane = q*16 + n holds batch row (rt*16+n), same k packing
// ushort index: (grp*NCHUNK + c)*512 + (q*16 + n)*8 + e   where k = c*32 + q*8 + e

// ---- pack [w_ih | w_hh] -> swizzled bf16 W', bias = b_ih + b_hh ----
__global__ void k_convert(const float* __restrict__ w_ih, const float* __restrict__ w_hh,
                          const float* __restrict__ b_ih, const float* __restrict__ b_hh,
                          ushort_t* __restrict__ Wp, float* __restrict__ bias) {
    const int grp = blockIdx.x;                  // 0..1023
    for (int i = threadIdx.x; i < 16 * KDIM; i += 256) {
        int r = i / KDIM;                        // row within group 0..15
        int k = i - r * KDIM;
        int g = grp * 16 + r;                    // gate row 0..16383
        float v = (k < NINP) ? w_ih[(size_t)g * NINP + k]
                             : w_hh[(size_t)g * NHID + (k - NINP)];
        int c = k >> 5, q = (k >> 3) & 3, e = k & 7;
        Wp[((size_t)grp * NCHUNK + c) * 512 + (q * 16 + r) * 8 + e] = f2b(v);
    }
    if (threadIdx.x < 16) {
        int g = grp * 16 + threadIdx.x;
        bias[g] = b_ih[g] + b_hh[g];
    }
}

// ---- init A0' = [emb(tokens[0]) | 0] (swizzled), c = 0 ----
__global__ void k_init(const int* __restrict__ tokens, const float* __restrict__ emb,
                       ushort_t* __restrict__ A0, float* __restrict__ cbuf) {
    int idx = blockIdx.x * 256 + threadIdx.x;
    if (idx < BATCH * KDIM) {
        int b = idx / KDIM, k = idx - b * KDIM;
        float v = (k < NINP) ? emb[tokens[b] * NINP + k] : 0.f;
        int c = k >> 5, q = (k >> 3) & 3, e = k & 7;
        A0[((size_t)(b >> 4) * NCHUNK + c) * 512 + (q * 16 + (b & 15)) * 8 + e] = f2b(v);
    }
    if (idx < BATCH * NHID) cbuf[idx] = 0.f;
}

// ---- one LSTM step ----
// grid 256 blocks (16 hidden cols each: 4 gate types x 16 = 64 output cols),
// 512 threads = 8 waves, K split across waves; LDS-atomic reduction.
__global__ __launch_bounds__(512)
void k_step(int t, const ushort_t* __restrict__ Wp, const float* __restrict__ bias,
            const ushort_t* __restrict__ Ac, ushort_t* __restrict__ An,
            float* __restrict__ cbuf, float* __restrict__ out,
            const int* __restrict__ tokens, const int* __restrict__ seq_len,
            const float* __restrict__ emb) {
    const int tid  = threadIdx.x;
    const int wave = tid >> 6;
    const int lane = tid & 63;
    const int bx   = blockIdx.x;
    const int j0   = bx * 16;

    __shared__ float sbuf[BATCH][66];   // [batch][gt*16 + n], pad to 66 for banks

    // zero the reduction buffer
    for (int i = tid; i < BATCH * 66; i += 512)
        (&sbuf[0][0])[i] = 0.f;

    // block 0: write next step's embedding rows into An (independent of the K loop)
    if (bx == 0 && (t + 1) < TSTEPS) {
        for (int i = tid; i < BATCH * NINP; i += 512) {
            int b = i >> 6, k = i & 63;
            int tok = tokens[(t + 1) * BATCH + b];
            float v = emb[tok * NINP + k];
            int c = k >> 5, q = (k >> 3) & 3, e = k & 7;
            An[((size_t)(b >> 4) * NCHUNK + c) * 512 + (q * 16 + (b & 15)) * 8 + e] = f2b(v);
        }
    }
    __syncthreads();

    // K-chunk range for this wave: waves 0,1 take 17 chunks, waves 2..7 take 16 (sum=130)
    const int cstart = wave * 16 + (wave < 2 ? wave : 2);
    const int cend   = cstart + (wave < 2 ? 17 : 16);

    // fragment-stream base pointers (ushort units), each advances 512/chunk
    const ushort_t* pw0 = Wp + ((size_t)(0 * 256 + bx) * NCHUNK) * 512 + lane * 8;
    const ushort_t* pw1 = Wp + ((size_t)(1 * 256 + bx) * NCHUNK) * 512 + lane * 8;
    const ushort_t* pw2 = Wp + ((size_t)(2 * 256 + bx) * NCHUNK) * 512 + lane * 8;
    const ushort_t* pw3 = Wp + ((size_t)(3 * 256 + bx) * NCHUNK) * 512 + lane * 8;
    const ushort_t* pa0 = Ac + ((size_t)0 * NCHUNK) * 512 + lane * 8;
    const ushort_t* pa1 = Ac + ((size_t)1 * NCHUNK) * 512 + lane * 8;
    const ushort_t* pa2 = Ac + ((size_t)2 * NCHUNK) * 512 + lane * 8;
    const ushort_t* pa3 = Ac + ((size_t)3 * NCHUNK) * 512 + lane * 8;

    f32x4 acc[4][4];                     // [rt batch-tile][gt]
    #pragma unroll
    for (int rt = 0; rt < 4; ++rt)
        #pragma unroll
        for (int gt = 0; gt < 4; ++gt)
            acc[rt][gt] = (f32x4){0.f, 0.f, 0.f, 0.f};

    #define LOADF(dstW, dstA, c)                                              \
        do {                                                                  \
            size_t off = (size_t)(c) * 512;                                   \
            dstW[0] = *reinterpret_cast<const bf16x8*>(pw0 + off);            \
            dstW[1] = *reinterpret_cast<const bf16x8*>(pw1 + off);            \
            dstW[2] = *reinterpret_cast<const bf16x8*>(pw2 + off);            \
            dstW[3] = *reinterpret_cast<const bf16x8*>(pw3 + off);            \
            dstA[0] = *reinterpret_cast<const bf16x8*>(pa0 + off);            \
            dstA[1] = *reinterpret_cast<const bf16x8*>(pa1 + off);            \
            dstA[2] = *reinterpret_cast<const bf16x8*>(pa2 + off);            \
            dstA[3] = *reinterpret_cast<const bf16x8*>(pa3 + off);            \
        } while (0)

    bf16x8 curW[4], curA[4], nxtW[4], nxtA[4];
    LOADF(curW, curA, cstart);

    for (int c = cstart; c < cend - 1; ++c) {
        LOADF(nxtW, nxtA, c + 1);
        #pragma unroll
        for (int rt = 0; rt < 4; ++rt)
            #pragma unroll
            for (int gt = 0; gt < 4; ++gt)
                acc[rt][gt] = __builtin_amdgcn_mfma_f32_16x16x32_bf16(
                    curA[rt], curW[gt], acc[rt][gt], 0, 0, 0);
        #pragma unroll
        for (int z = 0; z < 4; ++z) { curW[z] = nxtW[z]; curA[z] = nxtA[z]; }
    }
    #pragma unroll
    for (int rt = 0; rt < 4; ++rt)
        #pragma unroll
        for (int gt = 0; gt < 4; ++gt)
            acc[rt][gt] = __builtin_amdgcn_mfma_f32_16x16x32_bf16(
                curA[rt], curW[gt], acc[rt][gt], 0, 0, 0);
    #undef LOADF

    // cross-wave reduction: C/D layout col = lane&15 (gate col n), row = (lane>>4)*4 + r
    {
        const int n = lane & 15, q = lane >> 4;
        #pragma unroll
        for (int rt = 0; rt < 4; ++rt)
            #pragma unroll
            for (int gt = 0; gt < 4; ++gt)
                #pragma unroll
                for (int r = 0; r < 4; ++r)
                    atomicAdd(&sbuf[rt * 16 + q * 4 + r][gt * 16 + n], acc[rt][gt][r]);
    }
    __syncthreads();

    // cell update: thread (wave, lane) handles batch b=lane, local cols jl=wave, wave+8
    {
        const int b  = lane;
        const int sl = seq_len[b];
        const bool valid = (t < sl) || (t == 0);
        #pragma unroll
        for (int jj = 0; jj < 2; ++jj) {
            int jl = wave + jj * 8;               // 0..15
            int j  = j0 + jl;
            float ig = sbuf[b][ 0 + jl] + bias[          j];
            float fg = sbuf[b][16 + jl] + bias[    NHID + j];
            float gg = sbuf[b][32 + jl] + bias[2 * NHID + j];
            float og = sbuf[b][48 + jl] + bias[3 * NHID + j];
            int cidx = b * NHID + j;
            float cold = cbuf[cidx];
            float cn = sigf(fg) * cold + sigf(ig) * tanhf(gg);
            float hn = sigf(og) * tanhf(cn);
            cbuf[cidx] = cn;
            if (valid) out[cidx] = cn;
            int kk = NINP + j;                    // position in A' k-dim
            int c = kk >> 5, q = (kk >> 3) & 3, e = kk & 7;
            An[((size_t)(b >> 4) * NCHUNK + c) * 512 + (q * 16 + (b & 15)) * 8 + e] = f2b(hn);
        }
    }
}

extern "C" void kernel_launch(void* const* d_in, const int* in_sizes, int n_in,
                              void* d_out, int out_size, void* d_ws, size_t ws_size,
                              hipStream_t stream) {
    const int*   tokens  = (const int*)d_in[0];
    const int*   seq_len = (const int*)d_in[1];
    const float* emb     = (const float*)d_in[2];
    const float* w_ih    = (const float*)d_in[3];
    const float* w_hh    = (const float*)d_in[4];
    const float* b_ih    = (const float*)d_in[5];
    const float* b_hh    = (const float*)d_in[6];
    float* out = (float*)d_out;

    char* ws = (char*)d_ws;
    const size_t W_BYTES    = (size_t)NGRP * NCHUNK * 512 * 2;  // 136,314,880
    const size_t BIAS_BYTES = (size_t)NGATE * 4;
    const size_t C_BYTES    = (size_t)BATCH * NHID * 4;
    const size_t A_BYTES    = (size_t)4 * NCHUNK * 512 * 2;     // 532,480

    ushort_t* Wp   = (ushort_t*)ws;
    float*    bias = (float*)(ws + W_BYTES);
    float*    cbuf = (float*)(ws + W_BYTES + BIAS_BYTES);
    ushort_t* A0   = (ushort_t*)(ws + W_BYTES + BIAS_BYTES + C_BYTES);
    ushort_t* A1   = (ushort_t*)(ws + W_BYTES + BIAS_BYTES + C_BYTES + A_BYTES);

    k_convert<<<NGRP, 256, 0, stream>>>(w_ih, w_hh, b_ih, b_hh, Wp, bias);

    int init_elems = BATCH * KDIM;
    k_init<<<(init_elems + 255) / 256, 256, 0, stream>>>(tokens, emb, A0, cbuf);

    for (int t = 0; t < TSTEPS; ++t) {
        ushort_t* Acur  = (t & 1) ? A1 : A0;
        ushort_t* Anext = (t & 1) ? A0 : A1;
        k_step<<<256, 512, 0, stream>>>(t, Wp, bias, Acur, Anext, cbuf, out,
                                        tokens, seq_len, emb);
    }
}